// Round 15
// baseline (448.207 us; speedup 1.0000x reference)
//
#include <hip/hip_runtime.h>

// ---------------------------------------------------------------------------
// LRU single step — v16: BARRIER-FREE dual GEMM via E-formulation.
//   state = Lambda * x0 + Bn @ u          (PLANAR re|im, f32)
//   y     = C1@x0_re + C2@x0_im + (E+D)@u    [independent of state!]
//     C1 = C_re.lam_re - C_im.lam_im ; C2 = -(C_re.lam_im + C_im.lam_re)
//     E  = (C_re@ (B_re.g) - C_im@ (B_im.g))   (f32-accum prep, bf16 stored)
//
// Ladder: v2 192. v3 247 "frag-I/O bad" -- CONFOUNDED (was 4blk/CU window;
//  v4 linear I/O same window was WORSE: 426 vs 344 MB). v7 195. v10 176 WIN
//  (nt-loads). v8/v11/v14/v15 NULL. v12/v13 REGRESS. Invariant: every
//  barrier-chained variant pins issue density at ~18%.
// v16: remove the barriers themselves. E-form kills the GEMM->GEMM dep;
//  W1 rows re-interleaved (quad parity = re/im plane, lane f32x4 = 4 consec
//  h) kills the Sc round-trip: fragment epilogue + fragment stores write
//  fully-covered 64B lines. ONE barrier total (post-staging). One 80KiB
//  XOR-swizzled LDS buffer Xb=[x0_re|x0_im|u] bf16 feeds both GEMMs;
//  2 blk/CU pinned (window 246MB < L3, v13-S proven). 16 free-running
//  waves/CU hide weight-load latency (m114 wave-overlap, finally unblocked).
// ---------------------------------------------------------------------------

typedef __attribute__((ext_vector_type(8))) short bf16x8;
typedef __attribute__((ext_vector_type(4))) float f32x4;
typedef unsigned short u16;

#define N_ROWS 32768
#define IN_DIM 256
#define SD 512
#define OUT_DIM 256
#define ROWS 32          // rows (n) per block
#define NTHR 512         // 8 waves
#define XP 1280          // Xb pitch u16 -- EXACT (80KiB x2 = 160KiB); banks
                         // handled by chunk XOR swizzle, not padding

#define MFMA16(a, b, c) __builtin_amdgcn_mfma_f32_16x16x32_bf16(a, b, c, 0, 0, 0)

__device__ __align__(16) float g_lam[2 * SD];            // lam_re | lam_im
__device__ __align__(16) u16   g_W1[1024 * IN_DIM];      // interleaved quad layout
__device__ __align__(16) u16   g_Wy[OUT_DIM * 1280];     // [C1 | C2 | E+D]

__device__ __forceinline__ u16 f2b(float f) {
    union { float f; unsigned int u; } v; v.f = f;
    unsigned int r = v.u + 0x7FFFu + ((v.u >> 16) & 1u);   // RNE
    return (u16)(r >> 16);
}
__device__ __forceinline__ ushort4 f2b4(f32x4 v) {
    ushort4 b;
    b.x = f2b(v[0]); b.y = f2b(v[1]); b.z = f2b(v[2]); b.w = f2b(v[3]);
    return b;
}

// --- combined prep (single launch, all blocks self-contained) ---------------
// blocks [0,1024):    W1 interleaved row b
// blocks [1024,1280): Wy C1|C2 for o = b-1024
// blocks [1280,1536): Wy E+D  for o = b-1280   (LDS-staged coalesced GEMV)
// blocks [1536,1538): g_lam
__global__ void prep_all(const float* __restrict__ nu_log,
                         const float* __restrict__ theta_log,
                         const float* __restrict__ gamma_log,
                         const float* __restrict__ B_re, const float* __restrict__ B_im,
                         const float* __restrict__ C_re, const float* __restrict__ C_im,
                         const float* __restrict__ D) {
    __shared__ float ar[SD], ai[SD];
    int b = blockIdx.x, t = threadIdx.x;
    if (b < 1024) {
        // W1 row R: 16-row fragment = [re(h0..3) | im(h0..3) | re(h4..7) | im(h4..7)]
        // => output-fragment lane (quad,reg): plane = quad&1, h = base+(quad>>1)*4+reg
        int s = b >> 8, q = b & 255;
        int wv2 = q >> 5, rem = q & 31, ht = rem >> 4, r16 = rem & 15;
        int qd = r16 >> 2, rg = r16 & 3;
        int h = s * 128 + wv2 * 16 + ht * 8 + ((qd >> 1) << 2) + rg;
        const float* src = (qd & 1) ? B_im : B_re;
        g_W1[b * IN_DIM + t] = f2b(src[h * IN_DIM + t] * expf(gamma_log[h]));
    } else if (b < 1280) {
        int o = b - 1024;
        #pragma unroll
        for (int it = 0; it < 4; ++it) {
            int c = it * 256 + t;              // [0,1024)
            int h = c & 511, part = c >> 9;
            float mod = expf(-expf(nu_log[h]));
            float th  = expf(theta_log[h]);
            float lre = mod * cosf(th), lim = mod * sinf(th);
            float cr = C_re[o * SD + h], ci = C_im[o * SD + h];
            float v = part ? -(cr * lim + ci * lre) : (cr * lre - ci * lim);
            g_Wy[(size_t)o * 1280 + part * 512 + h] = f2b(v);
        }
    } else if (b < 1536) {
        int o = b - 1280, j = t;
        for (int h = t; h < SD; h += 256) {
            float g = expf(gamma_log[h]);
            ar[h] = C_re[o * SD + h] * g;
            ai[h] = C_im[o * SD + h] * g;
        }
        __syncthreads();
        float acc = 0.f;
        #pragma unroll 8
        for (int h = 0; h < SD; ++h)           // coalesced across j; L2-resident
            acc += ar[h] * B_re[h * IN_DIM + j] - ai[h] * B_im[h * IN_DIM + j];
        g_Wy[(size_t)o * 1280 + 1024 + j] = f2b(acc + D[o * IN_DIM + j]);
    } else {
        int h = (b - 1536) * 256 + t;          // [0,512)
        float mod = expf(-expf(nu_log[h]));
        float th  = expf(theta_log[h]);
        g_lam[h]      = mod * cosf(th);
        g_lam[SD + h] = mod * sinf(th);
    }
}

// --- main fused kernel: ONE barrier ----------------------------------------
__global__ __launch_bounds__(NTHR, 4) void lru_main(
    const float* __restrict__ u, const float* __restrict__ x0_re,
    const float* __restrict__ x0_im,
    float* __restrict__ y_out, float* __restrict__ st_out,
    long long st_limit)     // floats available in the state region of d_out
{
    __shared__ __align__(16) u16 Xb[ROWS * XP];   // 81,920 B -> 2 blk/CU exact

    const int tid  = threadIdx.x;
    const int wv   = tid >> 6;          // [0,8)
    const int lane = tid & 63;
    const int quad = lane >> 4;
    const int l16  = lane & 15;
    const int kq   = quad * 8;
    const size_t n0 = (size_t)blockIdx.x * ROWS;

    const int Mb = wv * 32;             // wave's M base

    // ---- stage Xb = [x0_re(ch 0-63) | x0_im(64-127) | u(128-159)] bf16 ----
    // chunk swizzle: phys = chunk ^ (row & 7)  (within 8-chunk groups)
    #pragma unroll
    for (int i = 0; i < 4; ++i) {                 // x0_re: 2048 8-float items
        int it = tid + i * NTHR;
        int r = it >> 6, c8 = it & 63;
        const float* s = x0_re + (n0 + r) * SD + c8 * 8;
        f32x4 v0 = *(const f32x4*)s, v1 = *(const f32x4*)(s + 4);
        int ph = (c8 ^ (r & 7)) << 3;
        *(ushort4*)(&Xb[r * XP + ph])     = f2b4(v0);
        *(ushort4*)(&Xb[r * XP + ph + 4]) = f2b4(v1);
    }
    #pragma unroll
    for (int i = 0; i < 4; ++i) {                 // x0_im
        int it = tid + i * NTHR;
        int r = it >> 6, c8 = it & 63;
        const float* s = x0_im + (n0 + r) * SD + c8 * 8;
        f32x4 v0 = *(const f32x4*)s, v1 = *(const f32x4*)(s + 4);
        int ph = ((64 + c8) ^ (r & 7)) << 3;
        *(ushort4*)(&Xb[r * XP + ph])     = f2b4(v0);
        *(ushort4*)(&Xb[r * XP + ph + 4]) = f2b4(v1);
    }
    #pragma unroll
    for (int i = 0; i < 2; ++i) {                 // u (single-use: nt loads)
        int it = tid + i * NTHR;                  // [0,1024)
        int r = it >> 5, c8 = it & 31;
        const float* s = u + (n0 + r) * IN_DIM + c8 * 8;
        f32x4 v0 = __builtin_nontemporal_load((const f32x4*)s);
        f32x4 v1 = __builtin_nontemporal_load((const f32x4*)(s + 4));
        int ph = ((128 + c8) ^ (r & 7)) << 3;
        *(ushort4*)(&Xb[r * XP + ph])     = f2b4(v0);
        *(ushort4*)(&Xb[r * XP + ph + 4]) = f2b4(v1);
    }
    __syncthreads();                    // THE barrier. Everything below is
                                        // per-wave independent.

    // ---- GEMM-S x4 chunks + DIRECT fragment epilogue (no LDS round-trip) --
    const int im = quad & 1;            // quad parity = output plane
    for (int s = 0; s < 4; ++s) {
        const int hb = s * 128 + wv * 16;

        // x0 f32 at this chunk's fragment positions (issued early, cached)
        f32x4 xr[2][2], xi[2][2];
        #pragma unroll
        for (int ht = 0; ht < 2; ++ht)
            #pragma unroll
            for (int nt = 0; nt < 2; ++nt) {
                int n  = nt * 16 + l16;
                int h0 = hb + ht * 8 + ((quad >> 1) << 2);
                size_t off = (n0 + n) * SD + h0;
                xr[ht][nt] = *(const f32x4*)(x0_re + off);
                xi[ht][nt] = *(const f32x4*)(x0_im + off);
            }

        f32x4 acc[2][2];
        #pragma unroll
        for (int ht = 0; ht < 2; ++ht)
            #pragma unroll
            for (int nt = 0; nt < 2; ++nt)
                acc[ht][nt] = f32x4{0.f, 0.f, 0.f, 0.f};
        const u16* w1b = g_W1 + (size_t)(s * 256 + Mb) * IN_DIM;
        #pragma unroll
        for (int k0 = 0; k0 < IN_DIM; k0 += 32) {
            bf16x8 a[2], bb[2];
            #pragma unroll
            for (int ht = 0; ht < 2; ++ht)
                a[ht] = *(const bf16x8*)(w1b + (ht * 16 + l16) * IN_DIM + k0 + kq);
            int ck = 128 + ((k0 + kq) >> 3);
            #pragma unroll
            for (int nt = 0; nt < 2; ++nt) {
                int n = nt * 16 + l16;
                bb[nt] = *(const bf16x8*)(&Xb[n * XP + ((ck ^ (n & 7)) << 3)]);
            }
            acc[0][0] = MFMA16(a[0], bb[0], acc[0][0]);
            acc[0][1] = MFMA16(a[0], bb[1], acc[0][1]);
            acc[1][0] = MFMA16(a[1], bb[0], acc[1][0]);
            acc[1][1] = MFMA16(a[1], bb[1], acc[1][1]);
        }

        // epilogue: lane holds Bu for ITS plane (quad parity) at 4 consec h.
        // state = lam*x0 + Bu, f32 accumulators straight to 16B stores
        // (quads of an l16-group cover fully-written 64B lines).
        #pragma unroll
        for (int ht = 0; ht < 2; ++ht)
            #pragma unroll
            for (int nt = 0; nt < 2; ++nt) {
                int n  = nt * 16 + l16;
                int h0 = hb + ht * 8 + ((quad >> 1) << 2);
                f32x4 lre = *(const f32x4*)(g_lam + h0);
                f32x4 lim = *(const f32x4*)(g_lam + SD + h0);
                f32x4 p  = im ? xi[ht][nt] : xr[ht][nt];
                f32x4 q2 = im ? xr[ht][nt] : xi[ht][nt];
                f32x4 ls = im ? lim : -lim;
                f32x4 sv = lre * p + ls * q2 + acc[ht][nt];
                long long idx = (im ? (long long)N_ROWS * SD : 0ll)
                              + (long long)((n0 + n) * SD + h0);
                if (idx + 3 < st_limit) {
                    *(f32x4*)(st_out + idx) = sv;
                } else {
                    #pragma unroll
                    for (int k = 0; k < 4; ++k)
                        if (idx + k < st_limit) st_out[idx + k] = sv[k];
                }
            }
    }

    // ---- GEMM-Y: K=1280 streaming, independent of everything above --------
    f32x4 accy[2][2];
    #pragma unroll
    for (int ot = 0; ot < 2; ++ot)
        #pragma unroll
        for (int nt = 0; nt < 2; ++nt)
            accy[ot][nt] = f32x4{0.f, 0.f, 0.f, 0.f};
    #pragma unroll 8
    for (int k0 = 0; k0 < 1280; k0 += 32) {
        bf16x8 a[2], bb[2];
        #pragma unroll
        for (int ot = 0; ot < 2; ++ot)
            a[ot] = *(const bf16x8*)(g_Wy + (size_t)(Mb + ot * 16 + l16) * 1280
                                     + k0 + kq);
        int ck = (k0 + kq) >> 3;
        #pragma unroll
        for (int nt = 0; nt < 2; ++nt) {
            int n = nt * 16 + l16;
            bb[nt] = *(const bf16x8*)(&Xb[n * XP + ((ck ^ (n & 7)) << 3)]);
        }
        accy[0][0] = MFMA16(a[0], bb[0], accy[0][0]);
        accy[0][1] = MFMA16(a[0], bb[1], accy[0][1]);
        accy[1][0] = MFMA16(a[1], bb[0], accy[1][0]);
        accy[1][1] = MFMA16(a[1], bb[1], accy[1][1]);
    }

    // ---- y: DIRECT fragment stores (64B lines fully covered per l16-group)
    #pragma unroll
    for (int ot = 0; ot < 2; ++ot)
        #pragma unroll
        for (int nt = 0; nt < 2; ++nt) {
            int n  = nt * 16 + l16;
            int o0 = Mb + ot * 16 + quad * 4;
            *(f32x4*)(y_out + (size_t)(n0 + n) * OUT_DIM + o0) = accy[ot][nt];
        }
}

extern "C" void kernel_launch(void* const* d_in, const int* in_sizes, int n_in,
                              void* d_out, int out_size, void* d_ws, size_t ws_size,
                              hipStream_t stream) {
    const float* u         = (const float*)d_in[0];
    const float* x0_re     = (const float*)d_in[1];
    const float* x0_im     = (const float*)d_in[2];
    const float* nu_log    = (const float*)d_in[3];
    const float* theta_log = (const float*)d_in[4];
    const float* gamma_log = (const float*)d_in[5];
    const float* B_re      = (const float*)d_in[6];
    const float* B_im      = (const float*)d_in[7];
    const float* C_re      = (const float*)d_in[8];
    const float* C_im      = (const float*)d_in[9];
    const float* D         = (const float*)d_in[10];

    float* y_out  = (float*)d_out;
    float* st_out = y_out + (size_t)N_ROWS * OUT_DIM;
    long long st_limit = (long long)out_size - (long long)N_ROWS * OUT_DIM;

    prep_all<<<1538, 256, 0, stream>>>(nu_log, theta_log, gamma_log,
                                       B_re, B_im, C_re, C_im, D);
    lru_main<<<N_ROWS / ROWS, NTHR, 0, stream>>>(u, x0_re, x0_im,
                                                 y_out, st_out, st_limit);
}

// Round 16
// 360.426 us; speedup vs baseline: 1.2435x; 1.2435x over previous
//
#include <hip/hip_runtime.h>

// ---------------------------------------------------------------------------
// LRU single step, fused — v17 (v14 + inline-asm batched weight loads,
//                               counted vmcnt — the un-foldable pipeline).
//   state = Lambda * x0 + Bn @ u              (complex; stored PLANAR re|im)
//   y     = s_re @ C_re^T - s_im @ C_im^T + u @ D^T
//
// Ladder: v2 192. v3 247 fragment-I/O BAD (confirmed by v16: fragment
//  stores defeat write absorption). v4-v6 window BAD. v7 195. v10 176 WIN
//  (nt-loads). v8/v11/v14/v15 NULL (compiler folded every C-level pipeline;
//  VGPR stuck 60-64 => ~1 weight load in flight, 160 serialized L2 round
//  trips/wave = the 18%-issue invariant). v12/v13/v16 REGRESS.
// v17: inline-asm global_load_dwordx4 with "=v" outputs + counted
//  s_waitcnt vmcnt(N) + sched_barrier(0) (rule 18). Compiler cannot re-sink
//  asm. Per phase: 8 loads up front, steady-state 8-deep ring (slot reuse
//  after consumption; WAR safe: load completion >>200cy after MFMA reads).
//  vmcnt counting phase-safe: every phase starts at vmcnt=0 (__syncthreads
//  and phase-final vmcnt(0) both drain; LDS reads count lgkm only).
//  w[8]=32 VGPR, total ~112 < 128 -> 2 blk/CU preserved.
// Kept from v14: nt-loads, linear I/O, swapped-operand MFMA, dbuf Sc,
//  x0 prefetch one chunk ahead, 50,688B LDS.
// ---------------------------------------------------------------------------

typedef __attribute__((ext_vector_type(8))) short bf16x8;
typedef __attribute__((ext_vector_type(4))) float f32x4;
typedef unsigned short u16;

#define N_ROWS 32768
#define IN_DIM 256
#define SD 512
#define OUT_DIM 256
#define ROWS 32          // rows (n) per block
#define NTHR 512         // 8 waves
#define TP 264           // tile pitch in u16 (256 + 8 pad)
#define YP 260           // y staging pitch in f32
#define SMEM_U16 (3 * ROWS * TP)   // 50,688 B

#define MFMA16(a, b, c) __builtin_amdgcn_mfma_f32_16x16x32_bf16(a, b, c, 0, 0, 0)

// inline-asm 16B weight load: forced allocation, pinned issue order.
#define GLOAD16(dst, ptr)                                                   \
    asm volatile("global_load_dwordx4 %0, %1, off"                          \
                 : "=v"(dst) : "v"(ptr) : "memory")
// counted wait + scheduling fence (rule 18: MFMA can hoist past asm waitcnt)
#define VMWAIT(n)                                                           \
    do { asm volatile("s_waitcnt vmcnt(" #n ")" ::: "memory");              \
         __builtin_amdgcn_sched_barrier(0); } while (0)

__device__ __align__(16) float g_lam[2 * SD];            // lam_re | lam_im
__device__ __align__(16) u16   g_W1[1024 * IN_DIM];      // bf16
__device__ __align__(16) u16   g_Wy[OUT_DIM * 1280];     // bf16

__device__ __forceinline__ u16 f2b(float f) {
    union { float f; unsigned int u; } v; v.f = f;
    unsigned int r = v.u + 0x7FFFu + ((v.u >> 16) & 1u);   // RNE
    return (u16)(r >> 16);
}
__device__ __forceinline__ ushort4 f2b4(f32x4 v) {
    ushort4 b;
    b.x = f2b(v[0]); b.y = f2b(v[1]); b.z = f2b(v[2]); b.w = f2b(v[3]);
    return b;
}
__device__ __forceinline__ f32x4 b2f4(ushort4 b) {
    union { float f; unsigned int u; } t0, t1, t2, t3;
    t0.u = (unsigned)b.x << 16; t1.u = (unsigned)b.y << 16;
    t2.u = (unsigned)b.z << 16; t3.u = (unsigned)b.w << 16;
    return f32x4{t0.f, t1.f, t2.f, t3.f};
}

// --- combined prep (single launch) -----------------------------------------
__global__ void prep_all(const float* __restrict__ nu_log,
                         const float* __restrict__ theta_log,
                         const float* __restrict__ gamma_log,
                         const float* __restrict__ B_re, const float* __restrict__ B_im,
                         const float* __restrict__ C_re, const float* __restrict__ C_im,
                         const float* __restrict__ D) {
    int b = blockIdx.x, t = threadIdx.x;
    if (b < 1024) {
        int w = b & 255;
        int h = (b >> 8) * 128 + (w & 127);
        float g = expf(gamma_log[h]);
        const float* src = (w < 128) ? B_re : B_im;
        g_W1[b * IN_DIM + t] = f2b(src[h * IN_DIM + t] * g);
    } else if (b < 1280) {
        // Wy chunked: cols s*256+[0,128)=C_re[o][s*128+j],
        //             cols s*256+[128,256)=-C_im[o][s*128+j], [1024,1280)=D
        int o = b - 1024;
        #pragma unroll
        for (int it = 0; it < 5; ++it) {
            int c = it * 256 + t;
            float v;
            if (c < 1024) {
                int s = c >> 8, k = c & 255;
                v = (k < 128) ? C_re[o * SD + s * 128 + k]
                              : -C_im[o * SD + s * 128 + (k - 128)];
            } else {
                v = D[o * IN_DIM + (c - 1024)];
            }
            g_Wy[(size_t)o * 1280 + c] = f2b(v);
        }
    } else {
        int h = (b - 1280) * 256 + t;          // [0,512)
        float mod = expf(-expf(nu_log[h]));
        float th  = expf(theta_log[h]);
        g_lam[h]      = mod * cosf(th);
        g_lam[SD + h] = mod * sinf(th);
    }
}

// --- main fused kernel ------------------------------------------------------
__global__ __launch_bounds__(NTHR, 4) void lru_main(
    const float* __restrict__ u, const float* __restrict__ x0_re,
    const float* __restrict__ x0_im,
    float* __restrict__ y_out, float* __restrict__ st_out,
    long long st_limit)     // floats available in the state region of d_out
{
    __shared__ __align__(16) u16 SMEM[SMEM_U16];   // 50,688 B

    u16* Xu  = SMEM;                  // u tile bf16 [32][TP]
    u16* Sc0 = SMEM + ROWS * TP;      // state chunk bf16, ping
    u16* Sc1 = SMEM + 2 * ROWS * TP;  // state chunk bf16, pong

    const int tid  = threadIdx.x;
    const int wv   = tid >> 6;          // [0,8)
    const int lane = tid & 63;
    const int quad = lane >> 4;
    const int l16  = lane & 15;
    const int kq   = quad * 8;
    const size_t n0 = (size_t)blockIdx.x * ROWS;

    const int Mb = wv * 32;             // wave's M base within a 256-col chunk

    // linear epilogue / prefetch mapping: 1024 slots (32 rows x 32 j4)
    int en[2], ej[2];
    #pragma unroll
    for (int it = 0; it < 2; ++it) {
        int flat = it * NTHR + tid;
        en[it] = flat >> 5; ej[it] = flat & 31;
    }

    // prefetch x0 chunk 0 (nt: evict-first, don't thrash weight lines)
    f32x4 xr[2], xi[2];
    #pragma unroll
    for (int it = 0; it < 2; ++it) {
        size_t roff = (n0 + en[it]) * SD + ej[it] * 4;
        xr[it] = __builtin_nontemporal_load((const f32x4*)(x0_re + roff));
        xi[it] = __builtin_nontemporal_load((const f32x4*)(x0_im + roff));
    }

    // stage u tile -> bf16 LDS (32x256, linear nt f32x4 loads)
    #pragma unroll
    for (int i = 0; i < 4; ++i) {
        int it = tid + i * NTHR;              // 2048 items
        int r = it >> 6, c4 = it & 63;
        f32x4 v = __builtin_nontemporal_load(
            (const f32x4*)(u + (n0 + r) * IN_DIM) + c4);
        *(ushort4*)(&Xu[r * TP + c4 * 4]) = f2b4(v);
    }
    __syncthreads();                    // drains vmcnt -> 0

    f32x4 accy[2][2];
    #pragma unroll
    for (int ot = 0; ot < 2; ++ot)
        #pragma unroll
        for (int nt = 0; nt < 2; ++nt)
            accy[ot][nt] = f32x4{0.f, 0.f, 0.f, 0.f};

    // one GEMM phase: 8 k-steps, asm-batched weight pipe (8-deep ring),
    // LDS operand from Xs, accumulating into AC.
    // Entry invariant: vmcnt == 0.  Exit invariant: vmcnt == 0.
    #define GEMM_PHASE(AC, a0p, a1p, Xs)                                     \
    {                                                                        \
        bf16x8 w[8];                                                         \
        GLOAD16(w[0], (a0p));        GLOAD16(w[1], (a1p));                   \
        GLOAD16(w[2], (a0p) + 32);   GLOAD16(w[3], (a1p) + 32);              \
        GLOAD16(w[4], (a0p) + 64);   GLOAD16(w[5], (a1p) + 64);              \
        GLOAD16(w[6], (a0p) + 96);   GLOAD16(w[7], (a1p) + 96);              \
        _Pragma("unroll")                                                    \
        for (int kk = 0; kk < 8; ++kk) {                                     \
            const int s2 = (kk & 3) * 2;                                     \
            bf16x8 b0 = *(const bf16x8*)(&(Xs)[l16 * TP + kk * 32 + kq]);    \
            bf16x8 b1 = *(const bf16x8*)(&(Xs)[(16 + l16) * TP + kk * 32 + kq]);\
            if (kk < 4)      { VMWAIT(6); }                                  \
            else if (kk == 4){ VMWAIT(6); }                                  \
            else if (kk == 5){ VMWAIT(4); }                                  \
            else if (kk == 6){ VMWAIT(2); }                                  \
            else             { VMWAIT(0); }                                  \
            bf16x8 wa = w[s2], wb2 = w[s2 + 1];                              \
            AC[0][0] = MFMA16(wa, b0, AC[0][0]);                             \
            AC[0][1] = MFMA16(wa, b1, AC[0][1]);                             \
            AC[1][0] = MFMA16(wb2, b0, AC[1][0]);                            \
            AC[1][1] = MFMA16(wb2, b1, AC[1][1]);                            \
            if (kk < 4) {                                                    \
                GLOAD16(w[s2], (a0p) + (kk + 4) * 32);                       \
                GLOAD16(w[s2 + 1], (a1p) + (kk + 4) * 32);                   \
            }                                                                \
        }                                                                    \
    }

    for (int s = 0; s < 4; ++s) {
        u16* Sc = (s & 1) ? Sc1 : Sc0;        // double buffer
        const u16* w1b = g_W1 + (size_t)(s * 256 + Mb) * IN_DIM;
        const u16* a0p = w1b + l16 * IN_DIM + kq;
        const u16* a1p = w1b + (16 + l16) * IN_DIM + kq;

        // ---- GEMM-A (swapped): Bu[M=256(re|im)][n=32] = W1_chunk @ Xu^T
        f32x4 acc[2][2];
        #pragma unroll
        for (int ht = 0; ht < 2; ++ht)
            #pragma unroll
            for (int nt = 0; nt < 2; ++nt)
                acc[ht][nt] = f32x4{0.f, 0.f, 0.f, 0.f};
        GEMM_PHASE(acc, a0p, a1p, Xu);        // exits at vmcnt=0

        // fragments -> Sc as bf16 (contiguous ushort4: lane owns 4 consec h)
        #pragma unroll
        for (int ht = 0; ht < 2; ++ht)
            #pragma unroll
            for (int nt = 0; nt < 2; ++nt) {
                const int n  = nt * 16 + l16;
                const int hM = Mb + ht * 16 + quad * 4;
                *(ushort4*)(&Sc[n * TP + hM]) = f2b4(acc[ht][nt]);
            }
        __syncthreads();            // barrier A: Sc (Bu bf16) complete

        // ---- linear epilogue: in-place Sc update + contiguous f32 stores
        #pragma unroll
        for (int it = 0; it < 2; ++it) {
            const int n = en[it], j = ej[it];
            f32x4 br  = b2f4(*(const ushort4*)(&Sc[n * TP + j * 4]));
            f32x4 bi  = b2f4(*(const ushort4*)(&Sc[n * TP + 128 + j * 4]));
            f32x4 lre = *(const f32x4*)(g_lam + s * 128 + j * 4);
            f32x4 lim = *(const f32x4*)(g_lam + SD + s * 128 + j * 4);
            f32x4 sr = lre * xr[it] - lim * xi[it] + br;
            f32x4 si = lre * xi[it] + lim * xr[it] + bi;
            const long long ir = (long long)((n0 + n) * SD + s * 128 + j * 4);
            const long long ii = (long long)N_ROWS * SD + ir;
            if (ir + 3 < st_limit) {
                *(f32x4*)(st_out + ir) = sr;       // cacheable: L3 absorbs
            } else {
                #pragma unroll
                for (int k = 0; k < 4; ++k)
                    if (ir + k < st_limit) st_out[ir + k] = sr[k];
            }
            if (ii + 3 < st_limit) {
                *(f32x4*)(st_out + ii) = si;
            } else {
                #pragma unroll
                for (int k = 0; k < 4; ++k)
                    if (ii + k < st_limit) st_out[ii + k] = si[k];
            }
            *(ushort4*)(&Sc[n * TP + j * 4])       = f2b4(sr);
            *(ushort4*)(&Sc[n * TP + 128 + j * 4]) = f2b4(si);
        }

        // prefetch x0 for next chunk BEFORE barrier B (nt)
        if (s < 3) {
            #pragma unroll
            for (int it = 0; it < 2; ++it) {
                size_t roff = (n0 + en[it]) * SD + (s + 1) * 128 + ej[it] * 4;
                xr[it] = __builtin_nontemporal_load((const f32x4*)(x0_re + roff));
                xi[it] = __builtin_nontemporal_load((const f32x4*)(x0_im + roff));
            }
        }
        __syncthreads();            // barrier B: drains vmcnt -> 0

        // ---- partial y-GEMM (swapped): accy += Wy_chunk @ Sc^T
        const u16* wyb0 = g_Wy + (size_t)(Mb + l16) * 1280 + s * 256 + kq;
        const u16* wyb1 = g_Wy + (size_t)(Mb + 16 + l16) * 1280 + s * 256 + kq;
        GEMM_PHASE(accy, wyb0, wyb1, Sc);     // exits at vmcnt=0
        // no barrier: next chunk writes the OTHER Sc buffer
    }

    // ---- y u-part: accy += D @ Xu^T
    {
        const u16* wd0 = g_Wy + (size_t)(Mb + l16) * 1280 + 1024 + kq;
        const u16* wd1 = g_Wy + (size_t)(Mb + 16 + l16) * 1280 + 1024 + kq;
        GEMM_PHASE(accy, wd0, wd1, Xu);
    }

    // ---- y: fragments -> f32 LDS (all tiles dead) -> linear store
    __syncthreads();                // everyone done reading Xu/Sc0/Sc1
    float* Yf = (float*)SMEM;       // [32][YP]  (33,280 <= 50,688)
    #pragma unroll
    for (int ot = 0; ot < 2; ++ot)
        #pragma unroll
        for (int nt = 0; nt < 2; ++nt) {
            const int n   = nt * 16 + l16;
            const int col = Mb + ot * 16 + quad * 4;
            *(f32x4*)(&Yf[n * YP + col]) = accy[ot][nt];
        }
    __syncthreads();
    #pragma unroll
    for (int i = 0; i < 4; ++i) {
        int it = tid + i * NTHR;                  // 2048 items
        int r = it >> 6, c4 = it & 63;
        f32x4 v = *(const f32x4*)(&Yf[r * YP + c4 * 4]);
        *(f32x4*)(y_out + (n0 + r) * OUT_DIM + c4 * 4) = v;
    }
}

extern "C" void kernel_launch(void* const* d_in, const int* in_sizes, int n_in,
                              void* d_out, int out_size, void* d_ws, size_t ws_size,
                              hipStream_t stream) {
    const float* u         = (const float*)d_in[0];
    const float* x0_re     = (const float*)d_in[1];
    const float* x0_im     = (const float*)d_in[2];
    const float* nu_log    = (const float*)d_in[3];
    const float* theta_log = (const float*)d_in[4];
    const float* gamma_log = (const float*)d_in[5];
    const float* B_re      = (const float*)d_in[6];
    const float* B_im      = (const float*)d_in[7];
    const float* C_re      = (const float*)d_in[8];
    const float* C_im      = (const float*)d_in[9];
    const float* D         = (const float*)d_in[10];

    float* y_out  = (float*)d_out;
    float* st_out = y_out + (size_t)N_ROWS * OUT_DIM;
    long long st_limit = (long long)out_size - (long long)N_ROWS * OUT_DIM;

    prep_all<<<1282, 256, 0, stream>>>(nu_log, theta_log, gamma_log,
                                       B_re, B_im, C_re, C_im, D);
    lru_main<<<N_ROWS / ROWS, NTHR, 0, stream>>>(u, x0_re, x0_im,
                                                 y_out, st_out, st_limit);
}

// Round 17
// 280.466 us; speedup vs baseline: 1.5981x; 1.2851x over previous
//
#include <hip/hip_runtime.h>

// ---------------------------------------------------------------------------
// LRU single step, fused — v18 (v14 + fragment-packed weights: every weight
//                               load = ONE 1KB coalesced transaction).
//   state = Lambda * x0 + Bn @ u              (complex; stored PLANAR re|im)
//   y     = s_re @ C_re^T - s_im @ C_im^T + u @ D^T
//
// Ladder: v2 192. v3 frag global STORES bad (write amplification, confirmed
//  v16). v4-v6 window bad. v7 195. v10/v14 176 BEST (nt-loads; 3blk/CU null).
//  v8/v11/v15/v17 scheduling+depth levers ALL NULL (C-rolling, flat+
//  sched_barrier, inline-asm+counted-vmcnt: VGPR pinned 60-64, dur 176-207).
// v18 diagnosis: weight-load SHAPE, not depth. Each a[ht] load gathers 16
//  rows x 512B stride (16B each) -> ~16 L2 line requests per instruction,
//  serialized in the TA/TCP. 16 instr/phase x 16 = 256 L2 transactions --
//  a latency MULTIPLIER shared by every variant so far. Fix: prep packs
//  W1/Wy into exact fragment order [(phase,wv,ht,kk)][lane][8u16]; the load
//  becomes base + kk*1024B + lane*16B = one contiguous 1KB transaction
//  (SGPR base + imm offset). Same bytes, bit-identical numerics.
// Main kernel otherwise byte-identical to v14.
// ---------------------------------------------------------------------------

typedef __attribute__((ext_vector_type(8))) short bf16x8;
typedef __attribute__((ext_vector_type(4))) float f32x4;
typedef unsigned short u16;

#define N_ROWS 32768
#define IN_DIM 256
#define SD 512
#define OUT_DIM 256
#define ROWS 32          // rows (n) per block
#define NTHR 512         // 8 waves
#define TP 264           // tile pitch in u16 (256 + 8 pad)
#define YP 260           // y staging pitch in f32
#define SMEM_U16 (3 * ROWS * TP)   // 50,688 B

#define MFMA16(a, b, c) __builtin_amdgcn_mfma_f32_16x16x32_bf16(a, b, c, 0, 0, 0)

__device__ __align__(16) float g_lam[2 * SD];            // lam_re | lam_im
// fragment-packed: [(s*8+wv)*2+ht][kk][lane][8]  = (s*8+wv)*8192 + ht*4096
//                                                  + kk*512 + lane*8  (u16)
__device__ __align__(16) u16   g_W1[1024 * IN_DIM];      // 512 KB
__device__ __align__(16) u16   g_Wy[OUT_DIM * 1280];     // 640 KB (p=0..4)

__device__ __forceinline__ u16 f2b(float f) {
    union { float f; unsigned int u; } v; v.f = f;
    unsigned int r = v.u + 0x7FFFu + ((v.u >> 16) & 1u);   // RNE
    return (u16)(r >> 16);
}
__device__ __forceinline__ ushort4 f2b4(f32x4 v) {
    ushort4 b;
    b.x = f2b(v[0]); b.y = f2b(v[1]); b.z = f2b(v[2]); b.w = f2b(v[3]);
    return b;
}
__device__ __forceinline__ f32x4 b2f4(ushort4 b) {
    union { float f; unsigned int u; } t0, t1, t2, t3;
    t0.u = (unsigned)b.x << 16; t1.u = (unsigned)b.y << 16;
    t2.u = (unsigned)b.z << 16; t3.u = (unsigned)b.w << 16;
    return f32x4{t0.f, t1.f, t2.f, t3.f};
}

// --- combined prep (single launch) -----------------------------------------
__global__ void prep_all(const float* __restrict__ nu_log,
                         const float* __restrict__ theta_log,
                         const float* __restrict__ gamma_log,
                         const float* __restrict__ B_re, const float* __restrict__ B_im,
                         const float* __restrict__ C_re, const float* __restrict__ C_im,
                         const float* __restrict__ D) {
    int b = blockIdx.x, t = threadIdx.x;
    if (b < 1024) {
        // source semantics identical to v14 (chunked-planar row q of chunk s);
        // only the DESTINATION is fragment-packed.
        int s = b >> 8, q = b & 255;
        int wv = q >> 5, ht = (q >> 4) & 1, l16r = q & 15;
        int kk = t >> 5, quad = (t >> 3) & 3, e = t & 7;
        int j = q & 127;
        int h = s * 128 + j;
        float g = expf(gamma_log[h]);
        const float* src = (q < 128) ? B_re : B_im;
        size_t dst = ((((size_t)(s * 8 + wv) * 2 + ht) * 8 + kk) * 64
                      + quad * 16 + l16r) * 8 + e;
        g_W1[dst] = f2b(src[h * IN_DIM + t] * g);
    } else if (b < 1280) {
        // Wy value semantics identical to v14: phase p<4 cols [0,128)=C_re
        // chunk, [128,256)=-C_im chunk; p==4 = D. Destination packed.
        int o = b - 1024;
        int wv2 = o >> 5, ot = (o >> 4) & 1, l16o = o & 15;
        #pragma unroll
        for (int it = 0; it < 5; ++it) {
            int c = it * 256 + t;
            int p = c >> 8, k = c & 255;
            int kk = k >> 5, quad = (k >> 3) & 3, e = k & 7;
            float v;
            if (p < 4) {
                v = (k < 128) ? C_re[o * SD + p * 128 + k]
                              : -C_im[o * SD + p * 128 + (k - 128)];
            } else {
                v = D[o * IN_DIM + k];
            }
            size_t dst = ((((size_t)(p * 8 + wv2) * 2 + ot) * 8 + kk) * 64
                          + quad * 16 + l16o) * 8 + e;
            g_Wy[dst] = f2b(v);
        }
    } else {
        int h = (b - 1280) * 256 + t;          // [0,512)
        float mod = expf(-expf(nu_log[h]));
        float th  = expf(theta_log[h]);
        g_lam[h]      = mod * cosf(th);
        g_lam[SD + h] = mod * sinf(th);
    }
}

// --- main fused kernel ------------------------------------------------------
__global__ __launch_bounds__(NTHR, 4) void lru_main(
    const float* __restrict__ u, const float* __restrict__ x0_re,
    const float* __restrict__ x0_im,
    float* __restrict__ y_out, float* __restrict__ st_out,
    long long st_limit)     // floats available in the state region of d_out
{
    __shared__ __align__(16) u16 SMEM[SMEM_U16];   // 50,688 B

    u16* Xu  = SMEM;                  // u tile bf16 [32][TP]
    u16* Sc0 = SMEM + ROWS * TP;      // state chunk bf16, ping
    u16* Sc1 = SMEM + 2 * ROWS * TP;  // state chunk bf16, pong

    const int tid  = threadIdx.x;
    const int wv   = tid >> 6;          // [0,8)
    const int lane = tid & 63;
    const int quad = lane >> 4;
    const int l16  = lane & 15;
    const int kq   = quad * 8;
    const size_t n0 = (size_t)blockIdx.x * ROWS;

    const int Mb = wv * 32;             // wave's M base within a 256-col chunk

    // linear epilogue / prefetch mapping: 1024 slots (32 rows x 32 j4)
    int en[2], ej[2];
    #pragma unroll
    for (int it = 0; it < 2; ++it) {
        int flat = it * NTHR + tid;
        en[it] = flat >> 5; ej[it] = flat & 31;
    }

    // prefetch x0 chunk 0 (nt: evict-first, don't thrash weight lines)
    f32x4 xr[2], xi[2];
    #pragma unroll
    for (int it = 0; it < 2; ++it) {
        size_t roff = (n0 + en[it]) * SD + ej[it] * 4;
        xr[it] = __builtin_nontemporal_load((const f32x4*)(x0_re + roff));
        xi[it] = __builtin_nontemporal_load((const f32x4*)(x0_im + roff));
    }

    // stage u tile -> bf16 LDS (32x256, linear nt f32x4 loads)
    #pragma unroll
    for (int i = 0; i < 4; ++i) {
        int it = tid + i * NTHR;              // 2048 items
        int r = it >> 6, c4 = it & 63;
        f32x4 v = __builtin_nontemporal_load(
            (const f32x4*)(u + (n0 + r) * IN_DIM) + c4);
        *(ushort4*)(&Xu[r * TP + c4 * 4]) = f2b4(v);
    }
    __syncthreads();

    f32x4 accy[2][2];
    #pragma unroll
    for (int ot = 0; ot < 2; ++ot)
        #pragma unroll
        for (int nt = 0; nt < 2; ++nt)
            accy[ot][nt] = f32x4{0.f, 0.f, 0.f, 0.f};

    for (int s = 0; s < 4; ++s) {
        u16* Sc = (s & 1) ? Sc1 : Sc0;        // double buffer

        // ---- GEMM-A (swapped): Bu[M=256(re|im)][n=32] = W1_chunk @ Xu^T
        // weight loads: fragment-packed, base + kk*512 + lane*8 u16 ->
        // 64 lanes x 16B CONTIGUOUS = one 1KB transaction per load.
        f32x4 acc[2][2];
        #pragma unroll
        for (int ht = 0; ht < 2; ++ht)
            #pragma unroll
            for (int nt = 0; nt < 2; ++nt)
                acc[ht][nt] = f32x4{0.f, 0.f, 0.f, 0.f};
        const u16* w1b = g_W1 + (size_t)(s * 8 + wv) * 8192 + lane * 8;
        #pragma unroll
        for (int kk = 0; kk < 8; ++kk) {
            bf16x8 a[2], b[2];
            #pragma unroll
            for (int ht = 0; ht < 2; ++ht)
                a[ht] = *(const bf16x8*)(w1b + ht * 4096 + kk * 512);
            #pragma unroll
            for (int nt = 0; nt < 2; ++nt)
                b[nt] = *(const bf16x8*)(&Xu[(nt * 16 + l16) * TP + kk * 32 + kq]);
            #pragma unroll
            for (int ht = 0; ht < 2; ++ht)
                #pragma unroll
                for (int nt = 0; nt < 2; ++nt)
                    acc[ht][nt] = MFMA16(a[ht], b[nt], acc[ht][nt]);
        }
        // fragments -> Sc as bf16 (contiguous ushort4: lane owns 4 consec h)
        #pragma unroll
        for (int ht = 0; ht < 2; ++ht)
            #pragma unroll
            for (int nt = 0; nt < 2; ++nt) {
                const int n  = nt * 16 + l16;
                const int hM = Mb + ht * 16 + quad * 4;
                *(ushort4*)(&Sc[n * TP + hM]) = f2b4(acc[ht][nt]);
            }
        __syncthreads();            // barrier A: Sc (Bu bf16) complete

        // ---- linear epilogue: in-place Sc update + contiguous f32 stores
        #pragma unroll
        for (int it = 0; it < 2; ++it) {
            const int n = en[it], j = ej[it];
            f32x4 br  = b2f4(*(const ushort4*)(&Sc[n * TP + j * 4]));
            f32x4 bi  = b2f4(*(const ushort4*)(&Sc[n * TP + 128 + j * 4]));
            f32x4 lre = *(const f32x4*)(g_lam + s * 128 + j * 4);
            f32x4 lim = *(const f32x4*)(g_lam + SD + s * 128 + j * 4);
            f32x4 sr = lre * xr[it] - lim * xi[it] + br;
            f32x4 si = lre * xi[it] + lim * xr[it] + bi;
            const long long ir = (long long)((n0 + n) * SD + s * 128 + j * 4);
            const long long ii = (long long)N_ROWS * SD + ir;
            if (ir + 3 < st_limit) {
                *(f32x4*)(st_out + ir) = sr;       // cacheable: L3 absorbs
            } else {
                #pragma unroll
                for (int k = 0; k < 4; ++k)
                    if (ir + k < st_limit) st_out[ir + k] = sr[k];
            }
            if (ii + 3 < st_limit) {
                *(f32x4*)(st_out + ii) = si;
            } else {
                #pragma unroll
                for (int k = 0; k < 4; ++k)
                    if (ii + k < st_limit) st_out[ii + k] = si[k];
            }
            *(ushort4*)(&Sc[n * TP + j * 4])       = f2b4(sr);
            *(ushort4*)(&Sc[n * TP + 128 + j * 4]) = f2b4(si);
        }

        // prefetch x0 for next chunk BEFORE barrier B (nt)
        if (s < 3) {
            #pragma unroll
            for (int it = 0; it < 2; ++it) {
                size_t roff = (n0 + en[it]) * SD + (s + 1) * 128 + ej[it] * 4;
                xr[it] = __builtin_nontemporal_load((const f32x4*)(x0_re + roff));
                xi[it] = __builtin_nontemporal_load((const f32x4*)(x0_im + roff));
            }
        }
        __syncthreads();            // barrier B: Sc now bf16 state chunk

        // ---- partial y-GEMM (swapped): accy += Wy_chunk @ Sc^T
        const u16* wyb = g_Wy + (size_t)(s * 8 + wv) * 8192 + lane * 8;
        #pragma unroll
        for (int kk = 0; kk < 8; ++kk) {
            bf16x8 a[2], b[2];
            #pragma unroll
            for (int ot = 0; ot < 2; ++ot)
                a[ot] = *(const bf16x8*)(wyb + ot * 4096 + kk * 512);
            #pragma unroll
            for (int nt = 0; nt < 2; ++nt)
                b[nt] = *(const bf16x8*)(&Sc[(nt * 16 + l16) * TP + kk * 32 + kq]);
            #pragma unroll
            for (int ot = 0; ot < 2; ++ot)
                #pragma unroll
                for (int nt = 0; nt < 2; ++nt)
                    accy[ot][nt] = MFMA16(a[ot], b[nt], accy[ot][nt]);
        }
        // no barrier: next chunk writes the OTHER Sc buffer
    }

    // ---- y u-part: accy += D @ Xu^T  (packed phase p = 4)
    {
        const u16* wdb = g_Wy + (size_t)(4 * 8 + wv) * 8192 + lane * 8;
        #pragma unroll
        for (int kk = 0; kk < 8; ++kk) {
            bf16x8 a[2], b[2];
            #pragma unroll
            for (int ot = 0; ot < 2; ++ot)
                a[ot] = *(const bf16x8*)(wdb + ot * 4096 + kk * 512);
            #pragma unroll
            for (int nt = 0; nt < 2; ++nt)
                b[nt] = *(const bf16x8*)(&Xu[(nt * 16 + l16) * TP + kk * 32 + kq]);
            #pragma unroll
            for (int ot = 0; ot < 2; ++ot)
                #pragma unroll
                for (int nt = 0; nt < 2; ++nt)
                    accy[ot][nt] = MFMA16(a[ot], b[nt], accy[ot][nt]);
        }
    }

    // ---- y: fragments -> f32 LDS (all tiles dead) -> linear store
    __syncthreads();                // everyone done reading Xu/Sc0/Sc1
    float* Yf = (float*)SMEM;       // [32][YP]  (33,280 <= 50,688)
    #pragma unroll
    for (int ot = 0; ot < 2; ++ot)
        #pragma unroll
        for (int nt = 0; nt < 2; ++nt) {
            const int n   = nt * 16 + l16;
            const int col = Mb + ot * 16 + quad * 4;
            *(f32x4*)(&Yf[n * YP + col]) = accy[ot][nt];
        }
    __syncthreads();
    #pragma unroll
    for (int i = 0; i < 4; ++i) {
        int it = tid + i * NTHR;                  // 2048 items
        int r = it >> 6, c4 = it & 63;
        f32x4 v = *(const f32x4*)(&Yf[r * YP + c4 * 4]);
        *(f32x4*)(y_out + (n0 + r) * OUT_DIM + c4 * 4) = v;
    }
}

extern "C" void kernel_launch(void* const* d_in, const int* in_sizes, int n_in,
                              void* d_out, int out_size, void* d_ws, size_t ws_size,
                              hipStream_t stream) {
    const float* u         = (const float*)d_in[0];
    const float* x0_re     = (const float*)d_in[1];
    const float* x0_im     = (const float*)d_in[2];
    const float* nu_log    = (const float*)d_in[3];
    const float* theta_log = (const float*)d_in[4];
    const float* gamma_log = (const float*)d_in[5];
    const float* B_re      = (const float*)d_in[6];
    const float* B_im      = (const float*)d_in[7];
    const float* C_re      = (const float*)d_in[8];
    const float* C_im      = (const float*)d_in[9];
    const float* D         = (const float*)d_in[10];

    float* y_out  = (float*)d_out;
    float* st_out = y_out + (size_t)N_ROWS * OUT_DIM;
    long long st_limit = (long long)out_size - (long long)N_ROWS * OUT_DIM;

    prep_all<<<1282, 256, 0, stream>>>(nu_log, theta_log, gamma_log,
                                       B_re, B_im, C_re, C_im, D);
    lru_main<<<N_ROWS / ROWS, NTHR, 0, stream>>>(u, x0_re, x0_im,
                                                 y_out, st_out, st_limit);
}